// Round 8
// baseline (162.844 us; speedup 1.0000x reference)
//
#include <hip/hip_runtime.h>

#define NN 20000      // nodes
#define NPG 1000      // nodes per graph
#define NBG 20        // graphs
#define DD 128        // feature dim
#define KK2 256       // concat dim
#define KPC 50        // clusters per graph
#define KPAD 64       // padded cluster cols
#define NAC 1000      // total clusters
#define NACP 1024     // padded cluster cols
#define NPGP 1024     // padded nodes per graph (K dim of final GEMMs)
#define NEDGE 640000
#define CAP 96        // bucket capacity per node (mean deg 32, +11 sigma)

typedef __attribute__((ext_vector_type(8))) short bfrag;      // 8 bf16
typedef __attribute__((ext_vector_type(4))) float f32x4;
typedef __attribute__((ext_vector_type(8))) unsigned short ushort8;
typedef __attribute__((ext_vector_type(8))) _Float16 half8;

__device__ __forceinline__ unsigned short f2bf(float f) {
  unsigned int u = __builtin_bit_cast(unsigned int, f);
  unsigned int r = (u + 0x7FFFu + ((u >> 16) & 1u)) >> 16;   // RNE
  return (unsigned short)r;
}
__device__ __forceinline__ float bf2f(unsigned short u) {
  return __builtin_bit_cast(float, ((unsigned int)u) << 16);
}

// bijective XCD-chunk swizzle (m204 form)
__device__ __forceinline__ int xcd_swz(int orig, int nwg) {
  int q = nwg >> 3, r = nwg & 7;
  int x = orig & 7, idx = orig >> 3;
  return (x < r) ? (x * (q + 1) + idx) : (r * (q + 1) + (x - r) * q + idx);
}

// ================= stage 1: prep (build | cvt | wt_p | wt_f | wrow | vb) =================
__global__ __launch_bounds__(256) void k_prep(
    const float* __restrict__ h, const float* __restrict__ Wf,
    const float* __restrict__ Wp, const float* __restrict__ bp,
    const int* __restrict__ src, const int* __restrict__ dst,
    int* __restrict__ deg, int* __restrict__ ssrc,
    unsigned short* __restrict__ xb,
    unsigned short* __restrict__ Wtp, unsigned short* __restrict__ Wtf,
    unsigned short* __restrict__ Wpb,
    float* __restrict__ v, float* __restrict__ bb) {
  __shared__ float red[256];
  int b = blockIdx.x;
  int tid = threadIdx.x;
  if (b < 2500) {                       // ---- build ----
    int e = b * 256 + tid;
    if (e < NEDGE) {
      int d = dst[e];
      int pos = atomicAdd(&deg[d], 1);
      ssrc[d * CAP + pos] = src[e];
    }
  } else if (b < 3750) {                // ---- cvt h -> xb[:,0:128] ----
    int idx = (b - 2500) * 256 + tid;
    int n = idx >> 4, seg = idx & 15;
    const float4* hp = (const float4*)(h + n * DD + seg * 8);
    float4 x0 = hp[0], x1 = hp[1];
    ushort8 o;
    o[0] = f2bf(x0.x); o[1] = f2bf(x0.y); o[2] = f2bf(x0.z); o[3] = f2bf(x0.w);
    o[4] = f2bf(x1.x); o[5] = f2bf(x1.y); o[6] = f2bf(x1.z); o[7] = f2bf(x1.w);
    *(ushort8*)(xb + n * KK2 + seg * 8) = o;
  } else if (b < 4006) {                // ---- Wp -> Wtp (col-major bf16) ----
    int wid = tid >> 6, lane = tid & 63;
    int col = (b - 3750) * 4 + wid;
    #pragma unroll
    for (int i = 0; i < 4; ++i) {
      int kk = i * 64 + lane;
      float val = (col < NAC) ? Wp[kk * NAC + col] : 0.f;
      Wtp[col * KK2 + kk] = f2bf(val);
    }
  } else if (b < 4038) {                // ---- Wf -> Wtf (col-major bf16) ----
    int wid = tid >> 6, lane = tid & 63;
    int col = (b - 4006) * 4 + wid;
    #pragma unroll
    for (int i = 0; i < 4; ++i) {
      int kk = i * 64 + lane;
      Wtf[col * KK2 + kk] = f2bf(Wf[kk * DD + col]);
    }
  } else if (b < 4166) {                // ---- Wp -> Wpb (row-major bf16, padded) ----
    int idx = (b - 4038) * 256 + tid;
    int rrow = idx >> 7;
    int seg = idx & 127;
    ushort8 o;
    #pragma unroll
    for (int i = 0; i < 8; ++i) {
      int cc = seg * 8 + i;
      o[i] = (cc < NAC) ? f2bf(Wp[rrow * NAC + cc]) : (unsigned short)0;
    }
    *(ushort8*)(Wpb + rrow * NACP + seg * 8) = o;
  } else {                              // ---- v = Wp@bp, bb = ||bp||^2 ----
    int i = b - 4166;
    float acc = 0.f;
    for (int k = tid; k < NAC; k += 256) acc += Wp[i * NAC + k] * bp[k];
    red[tid] = acc;
    __syncthreads();
    for (int st = 128; st > 0; st >>= 1) {
      if (tid < st) red[tid] += red[tid + st];
      __syncthreads();
    }
    if (tid == 0) v[i] = red[0];
    if (i == 0) {
      __syncthreads();
      float a2 = 0.f;
      for (int k = tid; k < NAC; k += 256) { float t = bp[k]; a2 += t * t; }
      red[tid] = a2;
      __syncthreads();
      for (int st = 128; st > 0; st >>= 1) {
        if (tid < st) red[tid] += red[tid + st];
        __syncthreads();
      }
      if (tid == 0) *bb = red[0];
    }
  }
}

// ================= stage 2: gram2 (16 blocks) | aggregate (1250, rolling-8 gather) =================
__global__ __launch_bounds__(256) void k_mid(
    const unsigned short* __restrict__ Wpb, unsigned short* __restrict__ Gb,
    const int* __restrict__ deg, const int* __restrict__ ssrc,
    unsigned short* __restrict__ xb) {
  int b = blockIdx.x;
  int tid = threadIdx.x;
  if (b < 16) {                         // ---- G = Wp@Wp^T (256x256, K=1024) ----
    int i0 = (b & 3) * 64, j0 = (b >> 2) * 64;
    int wid = tid >> 6, lane = tid & 63;
    int lr = lane & 15, lg = lane >> 4;
    f32x4 acc[4] = {};
    for (int kt = 0; kt < 32; ++kt) {
      bfrag a[4], bfr;
      #pragma unroll
      for (int m = 0; m < 4; ++m)
        a[m] = *reinterpret_cast<const bfrag*>(Wpb + (size_t)(i0 + m * 16 + lr) * NACP + kt * 32 + lg * 8);
      bfr = *reinterpret_cast<const bfrag*>(Wpb + (size_t)(j0 + wid * 16 + lr) * NACP + kt * 32 + lg * 8);
      #pragma unroll
      for (int m = 0; m < 4; ++m)
        acc[m] = __builtin_amdgcn_mfma_f32_16x16x32_bf16(a[m], bfr, acc[m], 0, 0, 0);
    }
    #pragma unroll
    for (int m = 0; m < 4; ++m)
      #pragma unroll
      for (int r = 0; r < 4; ++r) {
        int row = i0 + m * 16 + lg * 4 + r;
        int col = j0 + wid * 16 + lr;
        Gb[row * 256 + col] = f2bf(acc[m][r]);
      }
  } else {                              // ---- mean aggregate: xb[:,128:256] ----
    int wg = xcd_swz(b - 16, 1250);
    int node = wg * 16 + (tid >> 4);
    int lane = tid & 15;                // 16 lanes x 8 bf16 = 128 cols
    int dg = deg[node];
    const int* sl = ssrc + node * CAP;
    float a[8] = {};
    int j = 0;
    for (; j + 8 <= dg; j += 8) {       // 8 gathers in flight
      int4 ia = *(const int4*)&sl[j];
      int4 ib = *(const int4*)&sl[j + 4];
      ushort8 w0 = *(const ushort8*)(xb + (size_t)ia.x * KK2 + lane * 8);
      ushort8 w1 = *(const ushort8*)(xb + (size_t)ia.y * KK2 + lane * 8);
      ushort8 w2 = *(const ushort8*)(xb + (size_t)ia.z * KK2 + lane * 8);
      ushort8 w3 = *(const ushort8*)(xb + (size_t)ia.w * KK2 + lane * 8);
      ushort8 w4 = *(const ushort8*)(xb + (size_t)ib.x * KK2 + lane * 8);
      ushort8 w5 = *(const ushort8*)(xb + (size_t)ib.y * KK2 + lane * 8);
      ushort8 w6 = *(const ushort8*)(xb + (size_t)ib.z * KK2 + lane * 8);
      ushort8 w7 = *(const ushort8*)(xb + (size_t)ib.w * KK2 + lane * 8);
      #pragma unroll
      for (int i = 0; i < 8; ++i)
        a[i] += ((bf2f(w0[i]) + bf2f(w1[i])) + (bf2f(w2[i]) + bf2f(w3[i]))) +
                ((bf2f(w4[i]) + bf2f(w5[i])) + (bf2f(w6[i]) + bf2f(w7[i])));
    }
    for (; j + 4 <= dg; j += 4) {
      int4 idx = *(const int4*)&sl[j];
      ushort8 v0 = *(const ushort8*)(xb + (size_t)idx.x * KK2 + lane * 8);
      ushort8 v1 = *(const ushort8*)(xb + (size_t)idx.y * KK2 + lane * 8);
      ushort8 v2 = *(const ushort8*)(xb + (size_t)idx.z * KK2 + lane * 8);
      ushort8 v3 = *(const ushort8*)(xb + (size_t)idx.w * KK2 + lane * 8);
      #pragma unroll
      for (int i = 0; i < 8; ++i)
        a[i] += bf2f(v0[i]) + bf2f(v1[i]) + bf2f(v2[i]) + bf2f(v3[i]);
    }
    for (; j < dg; ++j) {
      ushort8 vv = *(const ushort8*)(xb + (size_t)sl[j] * KK2 + lane * 8);
      #pragma unroll
      for (int i = 0; i < 8; ++i) a[i] += bf2f(vv[i]);
    }
    float inv = 1.f / (float)max(dg, 1);
    ushort8 o;
    #pragma unroll
    for (int i = 0; i < 8; ++i) o[i] = f2bf(a[i] * inv);
    *(ushort8*)(xb + node * KK2 + DD + lane * 8) = o;
  }
}

// ================= stage 3: fused norm(Gram) + window logits + softmax + feat =================
__global__ __launch_bounds__(256) void k_fused(
    const unsigned short* __restrict__ xb, const unsigned short* __restrict__ Gb,
    const unsigned short* __restrict__ Wtp, const unsigned short* __restrict__ Wtf,
    const float* __restrict__ bp, const float* __restrict__ bfeat,
    const float* __restrict__ v, const float* __restrict__ bbp,
    unsigned short* __restrict__ featb, _Float16* __restrict__ p_pad,
    unsigned short* __restrict__ pT) {
  __shared__ int4 xs4[1024];        // 32 rows x 32 slots (bf16x8), XOR-swizzled
  __shared__ float zbuf[32][52];
  __shared__ float nrm_lds[32];
  __shared__ float nrmf_lds[32];
  int n0 = blockIdx.x * 32;
  int tid = threadIdx.x;
  for (int i = tid; i < 1024; i += 256) {
    int row = i >> 5;
    xs4[i ^ (row & 7)] = ((const int4*)xb)[(size_t)(n0 + row) * 32 + (i & 31)];
  }
  if (tid < 32) { nrm_lds[tid] = 0.f; nrmf_lds[tid] = 0.f; }
  __syncthreads();

  int wid = tid >> 6, lane = tid & 63;
  int lr = lane & 15, lg = lane >> 4;
  const unsigned short* xsu = (const unsigned short*)xs4;

  // ---- Phase Y: y = x @ G, cols wid*64..+64; norm2 partial epilogue ----
  {
    f32x4 accy[2][4] = {};
    #pragma unroll
    for (int kt = 0; kt < 8; ++kt) {
      bfrag a[2], bfr[4];
      #pragma unroll
      for (int m = 0; m < 2; ++m) {
        int slot = (m * 16 + lr) * 32 + kt * 4 + lg;
        a[m] = *reinterpret_cast<const bfrag*>(&xs4[slot ^ ((slot >> 5) & 7)]);
      }
      #pragma unroll
      for (int c = 0; c < 4; ++c) {
        int j = wid * 64 + c * 16 + lr;
        bfr[c] = *reinterpret_cast<const bfrag*>(Gb + (size_t)j * KK2 + kt * 32 + lg * 8);
      }
      #pragma unroll
      for (int m = 0; m < 2; ++m)
        #pragma unroll
        for (int c = 0; c < 4; ++c)
          accy[m][c] = __builtin_amdgcn_mfma_f32_16x16x32_bf16(a[m], bfr[c], accy[m][c], 0, 0, 0);
    }
    float vv[4];
    #pragma unroll
    for (int c = 0; c < 4; ++c) vv[c] = v[wid * 64 + c * 16 + lr];
    #pragma unroll
    for (int m = 0; m < 2; ++m)
      #pragma unroll
      for (int r = 0; r < 4; ++r) {
        int row = m * 16 + lg * 4 + r;
        float part = 0.f;
        #pragma unroll
        for (int c = 0; c < 4; ++c) {
          int k = wid * 64 + c * 16 + lr;
          int slot = row * 32 + (k >> 3);
          float xv = bf2f(xsu[(size_t)(slot ^ (row & 7)) * 8 + (k & 7)]);
          part += (accy[m][c][r] + 2.f * vv[c]) * xv;
        }
        part += __shfl_xor(part, 1); part += __shfl_xor(part, 2);
        part += __shfl_xor(part, 4); part += __shfl_xor(part, 8);
        if (lr == 0) atomicAdd(&nrm_lds[row], part);
      }
  }

  // ---- Phase W: in-graph window logits (handles graph-straddling tiles) ----
  {
    int g0 = n0 / NPG;
    int g1 = (n0 + 31) / NPG;
    for (int gp = g0; gp <= g1; ++gp) {
      int wb = gp * KPC;
      f32x4 accw[2] = {};
      #pragma unroll
      for (int kt = 0; kt < 8; ++kt) {
        bfrag a[2], bfr;
        #pragma unroll
        for (int m = 0; m < 2; ++m) {
          int slot = (m * 16 + lr) * 32 + kt * 4 + lg;
          a[m] = *reinterpret_cast<const bfrag*>(&xs4[slot ^ ((slot >> 5) & 7)]);
        }
        bfr = *reinterpret_cast<const bfrag*>(Wtp + (size_t)(wb + wid * 16 + lr) * KK2 + kt * 32 + lg * 8);
        #pragma unroll
        for (int m = 0; m < 2; ++m)
          accw[m] = __builtin_amdgcn_mfma_f32_16x16x32_bf16(a[m], bfr, accw[m], 0, 0, 0);
      }
      int wc = wid * 16 + lr;
      float bias = (wc < KPC) ? bp[wb + wc] : 0.f;
      #pragma unroll
      for (int m = 0; m < 2; ++m)
        #pragma unroll
        for (int r = 0; r < 4; ++r) {
          int row = m * 16 + lg * 4 + r;
          if (wc < KPC && (n0 + row) / NPG == gp)
            zbuf[row][wc] = accw[m][r] + bias;
        }
    }
  }

  // ---- Phase F: feat GEMM, cols wid*32..+32 ----
  f32x4 accf[2][2] = {};
  {
    #pragma unroll
    for (int kt = 0; kt < 8; ++kt) {
      bfrag a[2], bfr[2];
      #pragma unroll
      for (int m = 0; m < 2; ++m) {
        int slot = (m * 16 + lr) * 32 + kt * 4 + lg;
        a[m] = *reinterpret_cast<const bfrag*>(&xs4[slot ^ ((slot >> 5) & 7)]);
      }
      #pragma unroll
      for (int c = 0; c < 2; ++c) {
        int col = wid * 32 + c * 16 + lr;
        bfr[c] = *reinterpret_cast<const bfrag*>(Wtf + (size_t)col * KK2 + kt * 32 + lg * 8);
      }
      #pragma unroll
      for (int m = 0; m < 2; ++m)
        #pragma unroll
        for (int c = 0; c < 2; ++c)
          accf[m][c] = __builtin_amdgcn_mfma_f32_16x16x32_bf16(a[m], bfr[c], accf[m][c], 0, 0, 0);
    }
    float nf[2][4] = {};
    #pragma unroll
    for (int c = 0; c < 2; ++c) {
      int col = wid * 32 + c * 16 + lr;
      float bias = bfeat[col];
      #pragma unroll
      for (int m = 0; m < 2; ++m)
        #pragma unroll
        for (int r = 0; r < 4; ++r) {
          float z = accf[m][c][r] + bias;
          accf[m][c][r] = z;
          nf[m][r] += z * z;
        }
    }
    #pragma unroll
    for (int m = 0; m < 2; ++m)
      #pragma unroll
      for (int r = 0; r < 4; ++r) {
        float p = nf[m][r];
        p += __shfl_xor(p, 1); p += __shfl_xor(p, 2);
        p += __shfl_xor(p, 4); p += __shfl_xor(p, 8);
        if (lr == 0) atomicAdd(&nrmf_lds[m * 16 + lg * 4 + r], p);
      }
  }
  __syncthreads();

  // feat write (bf16)
  #pragma unroll
  for (int m = 0; m < 2; ++m)
    #pragma unroll
    for (int r = 0; r < 4; ++r) {
      int row = m * 16 + lg * 4 + r;
      float sc = 1.f / fmaxf(sqrtf(nrmf_lds[row]), 1e-12f);
      #pragma unroll
      for (int c = 0; c < 2; ++c) {
        int col = wid * 32 + c * 16 + lr;
        featb[(size_t)(n0 + row) * DD + col] = f2bf(fmaxf(accf[m][c][r] * sc, 0.f));
      }
    }

  // softmax: 4 threads per node -> p_pad (fp16) and pT (bf16 [g][64][1024])
  if (tid < 128) {
    int node = tid >> 2, q = tid & 3;
    float nv = nrm_lds[node] + bbp[0];
    float inv = 1.f / fmaxf(sqrtf(fmaxf(nv, 0.f)), 1e-12f);
    float e[16];
    float mx = -1e30f;
    #pragma unroll
    for (int i = 0; i < 16; ++i) {
      int cc = q * 16 + i;
      float sv = (cc < KPC) ? fmaxf(zbuf[node][cc] * inv, 0.f) : -1e30f;
      e[i] = sv;
      mx = fmaxf(mx, sv);
    }
    mx = fmaxf(mx, __shfl_xor(mx, 1));
    mx = fmaxf(mx, __shfl_xor(mx, 2));
    float esum = 0.f;
    #pragma unroll
    for (int i = 0; i < 16; ++i) {
      int cc = q * 16 + i;
      float ev = (cc < KPC) ? __expf(e[i] - mx) : 0.f;
      e[i] = ev;
      esum += ev;
    }
    esum += __shfl_xor(esum, 1);
    esum += __shfl_xor(esum, 2);
    float isum = 1.f / esum;
    int n = n0 + node;
    int gg = n / NPG;
    int nloc = n - gg * NPG;
    half8 o0, o1;
    #pragma unroll
    for (int i = 0; i < 8; ++i) {
      o0[i] = (_Float16)(e[i] * isum);
      o1[i] = (_Float16)(e[i + 8] * isum);
    }
    *(half8*)&p_pad[(size_t)n * KPAD + q * 16] = o0;
    *(half8*)&p_pad[(size_t)n * KPAD + q * 16 + 8] = o1;
    #pragma unroll
    for (int i = 0; i < 16; ++i) {
      int cc = q * 16 + i;
      pT[((size_t)gg * KPAD + cc) * NPGP + nloc] = f2bf(e[i] * isum);
    }
  }
}

// ================= stage 4: a_s gather (625, rolling-8) =================
__global__ __launch_bounds__(256) void k_as(
    const _Float16* __restrict__ p_pad, const int* __restrict__ deg,
    const int* __restrict__ ssrc, float* __restrict__ asum_pad) {
  int wg = xcd_swz(blockIdx.x, 625);
  int n = wg * 32 + (threadIdx.x >> 3);
  int lane = threadIdx.x & 7;           // 8 lanes x 8 fp16 = 64 cols
  int dg = deg[n];
  const int* sl = ssrc + n * CAP;
  float a[8] = {};
  int j = 0;
  for (; j + 8 <= dg; j += 8) {         // 8 gathers in flight
    int4 ia = *(const int4*)&sl[j];
    int4 ib = *(const int4*)&sl[j + 4];
    half8 w0 = *(const half8*)(p_pad + (size_t)ia.x * KPAD + lane * 8);
    half8 w1 = *(const half8*)(p_pad + (size_t)ia.y * KPAD + lane * 8);
    half8 w2 = *(const half8*)(p_pad + (size_t)ia.z * KPAD + lane * 8);
    half8 w3 = *(const half8*)(p_pad + (size_t)ia.w * KPAD + lane * 8);
    half8 w4 = *(const half8*)(p_pad + (size_t)ib.x * KPAD + lane * 8);
    half8 w5 = *(const half8*)(p_pad + (size_t)ib.y * KPAD + lane * 8);
    half8 w6 = *(const half8*)(p_pad + (size_t)ib.z * KPAD + lane * 8);
    half8 w7 = *(const half8*)(p_pad + (size_t)ib.w * KPAD + lane * 8);
    #pragma unroll
    for (int i = 0; i < 8; ++i)
      a[i] += (((float)w0[i] + (float)w1[i]) + ((float)w2[i] + (float)w3[i])) +
              (((float)w4[i] + (float)w5[i]) + ((float)w6[i] + (float)w7[i]));
  }
  for (; j + 4 <= dg; j += 4) {
    int4 idx = *(const int4*)&sl[j];
    half8 v0 = *(const half8*)(p_pad + (size_t)idx.x * KPAD + lane * 8);
    half8 v1 = *(const half8*)(p_pad + (size_t)idx.y * KPAD + lane * 8);
    half8 v2 = *(const half8*)(p_pad + (size_t)idx.z * KPAD + lane * 8);
    half8 v3 = *(const half8*)(p_pad + (size_t)idx.w * KPAD + lane * 8);
    #pragma unroll
    for (int i = 0; i < 8; ++i)
      a[i] += (float)v0[i] + (float)v1[i] + (float)v2[i] + (float)v3[i];
  }
  for (; j < dg; ++j) {
    half8 vv = *(const half8*)(p_pad + (size_t)sl[j] * KPAD + lane * 8);
    #pragma unroll
    for (int i = 0; i < 8; ++i) a[i] += (float)vv[i];
  }
  float* dstp = asum_pad + (size_t)n * KPAD + lane * 8;
  *(float4*)dstp = make_float4(a[0], a[1], a[2], a[3]);
  *(float4*)(dstp + 4) = make_float4(a[4], a[5], a[6], a[7]);
}

// ================= stage 5: per-graph GEMMs h_pool = pT@feat, adj = pT@a_s =================
// Writes the ENTIRE output (in-block values + off-block zeros) -> no d_out memset needed.
__global__ __launch_bounds__(256) void k_final(
    const unsigned short* __restrict__ pT, const unsigned short* __restrict__ featb,
    const float* __restrict__ asum_pad, float* __restrict__ out) {
  __shared__ unsigned short ftT[128 * 72];   // [col][node], stride 72 (16B-aligned rows)
  __shared__ unsigned short asT[64 * 72];    // [k2][node]
  int g = blockIdx.x;
  int tid = threadIdx.x;
  int wid = tid >> 6, lane = tid & 63;
  int lr = lane & 15, lg = lane >> 4;
  int r = tid & 63;                     // staging node-row
  int cq = tid >> 6;                    // staging col-quarter

  // ---- zero off-block adj columns of this graph's 50 rows (disjoint from MFMA stores) ----
  {
    int cb0 = g * KPC;
    for (int l = tid; l < KPC * NAC; l += 256) {
      int rr2 = l / NAC, cc2 = l - (l / NAC) * NAC;
      unsigned int d = (unsigned int)(cc2 - cb0);
      if (d >= (unsigned int)KPC)
        out[(size_t)(g * KPC + rr2) * NAC + cc2] = 0.f;
    }
  }

  f32x4 acch[4][2] = {};                // h_pool: 4 row-frags x cols (wid*32 + c*16)
  f32x4 acca[4] = {};                   // adj: cols wid*16

  for (int t = 0; t < 16; ++t) {
    int nb = t * 64;
    int nloc = nb + r;
    // ---- stage feat tile (transposed): ftT[col][r] ----
    if (nloc < NPG) {
      const ushort8* fr = (const ushort8*)(featb + (size_t)(g * NPG + nloc) * DD + cq * 32);
      #pragma unroll
      for (int u = 0; u < 4; ++u) {
        ushort8 vv = fr[u];
        #pragma unroll
        for (int e2 = 0; e2 < 8; ++e2)
          ftT[(cq * 32 + u * 8 + e2) * 72 + r] = vv[e2];
      }
      const float4* ar = (const float4*)(asum_pad + (size_t)(g * NPG + nloc) * KPAD + cq * 16);
      #pragma unroll
      for (int u = 0; u < 4; ++u) {
        float4 av = ar[u];
        asT[(cq * 16 + u * 4 + 0) * 72 + r] = f2bf(av.x);
        asT[(cq * 16 + u * 4 + 1) * 72 + r] = f2bf(av.y);
        asT[(cq * 16 + u * 4 + 2) * 72 + r] = f2bf(av.z);
        asT[(cq * 16 + u * 4 + 3) * 72 + r] = f2bf(av.w);
      }
    } else {
      #pragma unroll
      for (int u = 0; u < 32; ++u) ftT[(cq * 32 + u) * 72 + r] = 0;
      #pragma unroll
      for (int u = 0; u < 16; ++u) asT[(cq * 16 + u) * 72 + r] = 0;
    }
    __syncthreads();
    // ---- A-frags from pT (global, contiguous; zero for pad cols) ----
    bfrag a[4][2];
    #pragma unroll
    for (int m = 0; m < 4; ++m)
      #pragma unroll
      for (int kk = 0; kk < 2; ++kk)
        a[m][kk] = *(const bfrag*)(pT + ((size_t)g * KPAD + m * 16 + lr) * NPGP + nb + kk * 32 + lg * 8);
    // ---- h_pool MFMAs ----
    #pragma unroll
    for (int c = 0; c < 2; ++c) {
      int col = wid * 32 + c * 16 + lr;
      #pragma unroll
      for (int kk = 0; kk < 2; ++kk) {
        bfrag bfv = *(const bfrag*)&ftT[col * 72 + kk * 32 + lg * 8];
        #pragma unroll
        for (int m = 0; m < 4; ++m)
          acch[m][c] = __builtin_amdgcn_mfma_f32_16x16x32_bf16(a[m][kk], bfv, acch[m][c], 0, 0, 0);
      }
    }
    // ---- adj MFMAs ----
    {
      int col2 = wid * 16 + lr;
      #pragma unroll
      for (int kk = 0; kk < 2; ++kk) {
        bfrag bfv = *(const bfrag*)&asT[col2 * 72 + kk * 32 + lg * 8];
        #pragma unroll
        for (int m = 0; m < 4; ++m)
          acca[m] = __builtin_amdgcn_mfma_f32_16x16x32_bf16(a[m][kk], bfv, acca[m], 0, 0, 0);
      }
    }
    __syncthreads();
  }
  // ---- plain stores (one writer per element) ----
  int k2 = wid * 16 + lr;
  #pragma unroll
  for (int m = 0; m < 4; ++m)
    #pragma unroll
    for (int rr = 0; rr < 4; ++rr) {
      int i = m * 16 + lg * 4 + rr;
      if (i < KPC) {
        #pragma unroll
        for (int c = 0; c < 2; ++c) {
          int col = wid * 32 + c * 16 + lr;
          out[1000000 + (size_t)(g * KPC + i) * DD + col] = acch[m][c][rr];
        }
        if (k2 < KPC)
          out[(size_t)(g * KPC + i) * NAC + g * KPC + k2] = acca[m][rr];
      }
    }
}

extern "C" void kernel_launch(void* const* d_in, const int* in_sizes, int n_in,
                              void* d_out, int out_size, void* d_ws, size_t ws_size,
                              hipStream_t stream) {
  const float* h = (const float*)d_in[0];
  const float* Wf = (const float*)d_in[1];
  const float* bf = (const float*)d_in[2];
  const float* Wp = (const float*)d_in[3];
  const float* bp = (const float*)d_in[4];
  const int* src = (const int*)d_in[5];
  const int* dst = (const int*)d_in[6];
  // d_in[7] (mask) unused: block-diagonal by construction.
  float* out = (float*)d_out;
  char* ws = (char*)d_ws;

  int* deg = (int*)(ws + 0);                                // 80 KB
  int* ssrc = (int*)(ws + 80000);                           // 7.68 MB
  unsigned short* xb = (unsigned short*)(ws + 7760000);     // 10.24 MB
  unsigned short* featb = (unsigned short*)(ws + 18004096); // 5.12 MB (bf16)
  _Float16* p_pad = (_Float16*)(ws + 23124992);             // 2.56 MB (fp16)
  float* asum_pad = (float*)(ws + 25690112);                // 5.12 MB
  unsigned short* Wpb = (unsigned short*)(ws + 30810112);   // 512 KB
  unsigned short* Gb = (unsigned short*)(ws + 31334400);    // 128 KB
  float* v = (float*)(ws + 31465472);                       // 1 KB
  float* bb = (float*)(ws + 31466496);                      // 1 KB
  unsigned short* Wtp = (unsigned short*)(ws + 31467520);   // 512 KB
  unsigned short* Wtf = (unsigned short*)(ws + 31991808);   // 64 KB
  unsigned short* pT = (unsigned short*)(ws + 32057344);    // 2.62 MB

  hipMemsetAsync(deg, 0, 80000, stream);

  k_prep<<<4422, 256, 0, stream>>>(h, Wf, Wp, bp, src, dst, deg, ssrc, xb, Wtp, Wtf, Wpb, v, bb);
  k_mid<<<1266, 256, 0, stream>>>(Wpb, Gb, deg, ssrc, xb);
  k_fused<<<625, 256, 0, stream>>>(xb, Gb, Wtp, Wtf, bp, bf, v, bb, featb, p_pad, pT);
  k_as<<<625, 256, 0, stream>>>(p_pad, deg, ssrc, asum_pad);
  k_final<<<NBG, 256, 0, stream>>>(pT, featb, asum_pad, out);
}

// Round 9
// 116.227 us; speedup vs baseline: 1.4011x; 1.4011x over previous
//
#include <hip/hip_runtime.h>

#define NN 20000      // nodes
#define NPG 1000      // nodes per graph
#define NBG 20        // graphs
#define DD 128        // feature dim
#define KK2 256       // concat dim
#define KPC 50        // clusters per graph
#define KPAD 64       // padded cluster cols
#define NAC 1000      // total clusters
#define NACP 1024     // padded cluster cols
#define NPGP 1024     // padded nodes per graph (K dim of final GEMMs)
#define NNT 20480     // stride of transposed node-major buffers
#define NEDGE 640000
#define CAP 96        // bucket capacity per node (mean deg 32, +11 sigma)

typedef __attribute__((ext_vector_type(8))) short bfrag;      // 8 bf16
typedef __attribute__((ext_vector_type(4))) float f32x4;
typedef __attribute__((ext_vector_type(8))) unsigned short ushort8;
typedef __attribute__((ext_vector_type(8))) _Float16 half8;

__device__ __forceinline__ unsigned short f2bf(float f) {
  unsigned int u = __builtin_bit_cast(unsigned int, f);
  unsigned int r = (u + 0x7FFFu + ((u >> 16) & 1u)) >> 16;   // RNE
  return (unsigned short)r;
}
__device__ __forceinline__ float bf2f(unsigned short u) {
  return __builtin_bit_cast(float, ((unsigned int)u) << 16);
}

// bijective XCD-chunk swizzle (m204 form)
__device__ __forceinline__ int xcd_swz(int orig, int nwg) {
  int q = nwg >> 3, r = nwg & 7;
  int x = orig & 7, idx = orig >> 3;
  return (x < r) ? (x * (q + 1) + idx) : (r * (q + 1) + (x - r) * q + idx);
}

// ================= stage 1: prep (build | cvt | wt_p | wt_f | wrow | vb | pT-zero) =================
__global__ __launch_bounds__(256) void k_prep(
    const float* __restrict__ h, const float* __restrict__ Wf,
    const float* __restrict__ Wp, const float* __restrict__ bp,
    const int* __restrict__ src, const int* __restrict__ dst,
    int* __restrict__ deg, int* __restrict__ ssrc,
    unsigned short* __restrict__ xb,
    unsigned short* __restrict__ Wtp, unsigned short* __restrict__ Wtf,
    unsigned short* __restrict__ Wpb,
    float* __restrict__ v, float* __restrict__ bb,
    unsigned short* __restrict__ pT) {
  __shared__ float red[256];
  int b = blockIdx.x;
  int tid = threadIdx.x;
  if (b < 2500) {                       // ---- build ----
    int e = b * 256 + tid;
    if (e < NEDGE) {
      int d = dst[e];
      int pos = atomicAdd(&deg[d], 1);
      ssrc[d * CAP + pos] = src[e];
    }
  } else if (b < 3750) {                // ---- cvt h -> xb[:,0:128] ----
    int idx = (b - 2500) * 256 + tid;
    int n = idx >> 4, seg = idx & 15;
    const float4* hp = (const float4*)(h + n * DD + seg * 8);
    float4 x0 = hp[0], x1 = hp[1];
    ushort8 o;
    o[0] = f2bf(x0.x); o[1] = f2bf(x0.y); o[2] = f2bf(x0.z); o[3] = f2bf(x0.w);
    o[4] = f2bf(x1.x); o[5] = f2bf(x1.y); o[6] = f2bf(x1.z); o[7] = f2bf(x1.w);
    *(ushort8*)(xb + n * KK2 + seg * 8) = o;
  } else if (b < 4006) {                // ---- Wp -> Wtp (col-major bf16) ----
    int wid = tid >> 6, lane = tid & 63;
    int col = (b - 3750) * 4 + wid;
    #pragma unroll
    for (int i = 0; i < 4; ++i) {
      int kk = i * 64 + lane;
      float val = (col < NAC) ? Wp[kk * NAC + col] : 0.f;
      Wtp[col * KK2 + kk] = f2bf(val);
    }
  } else if (b < 4038) {                // ---- Wf -> Wtf (col-major bf16) ----
    int wid = tid >> 6, lane = tid & 63;
    int col = (b - 4006) * 4 + wid;
    #pragma unroll
    for (int i = 0; i < 4; ++i) {
      int kk = i * 64 + lane;
      Wtf[col * KK2 + kk] = f2bf(Wf[kk * DD + col]);
    }
  } else if (b < 4166) {                // ---- Wp -> Wpb (row-major bf16, padded) ----
    int idx = (b - 4038) * 256 + tid;
    int rrow = idx >> 7;
    int seg = idx & 127;
    ushort8 o;
    #pragma unroll
    for (int i = 0; i < 8; ++i) {
      int cc = seg * 8 + i;
      o[i] = (cc < NAC) ? f2bf(Wp[rrow * NAC + cc]) : (unsigned short)0;
    }
    *(ushort8*)(Wpb + rrow * NACP + seg * 8) = o;
  } else if (b < 4422) {                // ---- v = Wp@bp, bb = ||bp||^2 ----
    int i = b - 4166;
    float acc = 0.f;
    for (int k = tid; k < NAC; k += 256) acc += Wp[i * NAC + k] * bp[k];
    red[tid] = acc;
    __syncthreads();
    for (int st = 128; st > 0; st >>= 1) {
      if (tid < st) red[tid] += red[tid + st];
      __syncthreads();
    }
    if (tid == 0) v[i] = red[0];
    if (i == 0) {
      __syncthreads();
      float a2 = 0.f;
      for (int k = tid; k < NAC; k += 256) { float t = bp[k]; a2 += t * t; }
      red[tid] = a2;
      __syncthreads();
      for (int st = 128; st > 0; st >>= 1) {
        if (tid < st) red[tid] += red[tid + st];
        __syncthreads();
      }
      if (tid == 0) *bb = red[0];
    }
  } else {                              // ---- zero ALL of pT (pad rows must be 0) ----
    int idx = (b - 4422) * 256 + tid;   // 640 blocks x 256 = 163840 int4 = 2.62 MB
    ((int4*)pT)[idx] = make_int4(0, 0, 0, 0);
  }
}

// ================= stage 2: gram2 (16 blocks) | aggregate (1250, rolling-8 gather) =================
__global__ __launch_bounds__(256) void k_mid(
    const unsigned short* __restrict__ Wpb, unsigned short* __restrict__ Gb,
    const int* __restrict__ deg, const int* __restrict__ ssrc,
    unsigned short* __restrict__ xb) {
  int b = blockIdx.x;
  int tid = threadIdx.x;
  if (b < 16) {                         // ---- G = Wp@Wp^T (256x256, K=1024) ----
    int i0 = (b & 3) * 64, j0 = (b >> 2) * 64;
    int wid = tid >> 6, lane = tid & 63;
    int lr = lane & 15, lg = lane >> 4;
    f32x4 acc[4] = {};
    for (int kt = 0; kt < 32; ++kt) {
      bfrag a[4], bfr;
      #pragma unroll
      for (int m = 0; m < 4; ++m)
        a[m] = *reinterpret_cast<const bfrag*>(Wpb + (size_t)(i0 + m * 16 + lr) * NACP + kt * 32 + lg * 8);
      bfr = *reinterpret_cast<const bfrag*>(Wpb + (size_t)(j0 + wid * 16 + lr) * NACP + kt * 32 + lg * 8);
      #pragma unroll
      for (int m = 0; m < 4; ++m)
        acc[m] = __builtin_amdgcn_mfma_f32_16x16x32_bf16(a[m], bfr, acc[m], 0, 0, 0);
    }
    #pragma unroll
    for (int m = 0; m < 4; ++m)
      #pragma unroll
      for (int r = 0; r < 4; ++r) {
        int row = i0 + m * 16 + lg * 4 + r;
        int col = j0 + wid * 16 + lr;
        Gb[row * 256 + col] = f2bf(acc[m][r]);
      }
  } else {                              // ---- mean aggregate: xb[:,128:256] ----
    int wg = xcd_swz(b - 16, 1250);
    int node = wg * 16 + (tid >> 4);
    int lane = tid & 15;                // 16 lanes x 8 bf16 = 128 cols
    int dg = deg[node];
    const int* sl = ssrc + node * CAP;
    float a[8] = {};
    int j = 0;
    for (; j + 8 <= dg; j += 8) {       // 8 gathers in flight
      int4 ia = *(const int4*)&sl[j];
      int4 ib = *(const int4*)&sl[j + 4];
      ushort8 w0 = *(const ushort8*)(xb + (size_t)ia.x * KK2 + lane * 8);
      ushort8 w1 = *(const ushort8*)(xb + (size_t)ia.y * KK2 + lane * 8);
      ushort8 w2 = *(const ushort8*)(xb + (size_t)ia.z * KK2 + lane * 8);
      ushort8 w3 = *(const ushort8*)(xb + (size_t)ia.w * KK2 + lane * 8);
      ushort8 w4 = *(const ushort8*)(xb + (size_t)ib.x * KK2 + lane * 8);
      ushort8 w5 = *(const ushort8*)(xb + (size_t)ib.y * KK2 + lane * 8);
      ushort8 w6 = *(const ushort8*)(xb + (size_t)ib.z * KK2 + lane * 8);
      ushort8 w7 = *(const ushort8*)(xb + (size_t)ib.w * KK2 + lane * 8);
      #pragma unroll
      for (int i = 0; i < 8; ++i)
        a[i] += ((bf2f(w0[i]) + bf2f(w1[i])) + (bf2f(w2[i]) + bf2f(w3[i]))) +
                ((bf2f(w4[i]) + bf2f(w5[i])) + (bf2f(w6[i]) + bf2f(w7[i])));
    }
    for (; j + 4 <= dg; j += 4) {
      int4 idx = *(const int4*)&sl[j];
      ushort8 v0 = *(const ushort8*)(xb + (size_t)idx.x * KK2 + lane * 8);
      ushort8 v1 = *(const ushort8*)(xb + (size_t)idx.y * KK2 + lane * 8);
      ushort8 v2 = *(const ushort8*)(xb + (size_t)idx.z * KK2 + lane * 8);
      ushort8 v3 = *(const ushort8*)(xb + (size_t)idx.w * KK2 + lane * 8);
      #pragma unroll
      for (int i = 0; i < 8; ++i)
        a[i] += bf2f(v0[i]) + bf2f(v1[i]) + bf2f(v2[i]) + bf2f(v3[i]);
    }
    for (; j < dg; ++j) {
      ushort8 vv = *(const ushort8*)(xb + (size_t)sl[j] * KK2 + lane * 8);
      #pragma unroll
      for (int i = 0; i < 8; ++i) a[i] += bf2f(vv[i]);
    }
    float inv = 1.f / (float)max(dg, 1);
    ushort8 o;
    #pragma unroll
    for (int i = 0; i < 8; ++i) o[i] = f2bf(a[i] * inv);
    *(ushort8*)(xb + node * KK2 + DD + lane * 8) = o;
  }
}

// ================= stage 3: fused norm(Gram) + window logits + softmax + feat(T) =================
__global__ __launch_bounds__(256) void k_fused(
    const unsigned short* __restrict__ xb, const unsigned short* __restrict__ Gb,
    const unsigned short* __restrict__ Wtp, const unsigned short* __restrict__ Wtf,
    const float* __restrict__ bp, const float* __restrict__ bfeat,
    const float* __restrict__ v, const float* __restrict__ bbp,
    unsigned short* __restrict__ featT, _Float16* __restrict__ p_pad,
    unsigned short* __restrict__ pT) {
  __shared__ int4 xs4[1024];        // 32 rows x 32 slots (bf16x8), XOR-swizzled; reused as ftl
  __shared__ float zbuf[32][52];
  __shared__ float nrm_lds[32];
  __shared__ float nrmf_lds[32];
  int n0 = blockIdx.x * 32;
  int tid = threadIdx.x;
  for (int i = tid; i < 1024; i += 256) {
    int row = i >> 5;
    xs4[i ^ (row & 7)] = ((const int4*)xb)[(size_t)(n0 + row) * 32 + (i & 31)];
  }
  if (tid < 32) { nrm_lds[tid] = 0.f; nrmf_lds[tid] = 0.f; }
  __syncthreads();

  int wid = tid >> 6, lane = tid & 63;
  int lr = lane & 15, lg = lane >> 4;
  const unsigned short* xsu = (const unsigned short*)xs4;

  // ---- Phase Y: y = x @ G, cols wid*64..+64; norm2 partial epilogue ----
  {
    f32x4 accy[2][4] = {};
    #pragma unroll
    for (int kt = 0; kt < 8; ++kt) {
      bfrag a[2], bfr[4];
      #pragma unroll
      for (int m = 0; m < 2; ++m) {
        int slot = (m * 16 + lr) * 32 + kt * 4 + lg;
        a[m] = *reinterpret_cast<const bfrag*>(&xs4[slot ^ ((slot >> 5) & 7)]);
      }
      #pragma unroll
      for (int c = 0; c < 4; ++c) {
        int j = wid * 64 + c * 16 + lr;
        bfr[c] = *reinterpret_cast<const bfrag*>(Gb + (size_t)j * KK2 + kt * 32 + lg * 8);
      }
      #pragma unroll
      for (int m = 0; m < 2; ++m)
        #pragma unroll
        for (int c = 0; c < 4; ++c)
          accy[m][c] = __builtin_amdgcn_mfma_f32_16x16x32_bf16(a[m], bfr[c], accy[m][c], 0, 0, 0);
    }
    float vv[4];
    #pragma unroll
    for (int c = 0; c < 4; ++c) vv[c] = v[wid * 64 + c * 16 + lr];
    #pragma unroll
    for (int m = 0; m < 2; ++m)
      #pragma unroll
      for (int r = 0; r < 4; ++r) {
        int row = m * 16 + lg * 4 + r;
        float part = 0.f;
        #pragma unroll
        for (int c = 0; c < 4; ++c) {
          int k = wid * 64 + c * 16 + lr;
          int slot = row * 32 + (k >> 3);
          float xv = bf2f(xsu[(size_t)(slot ^ (row & 7)) * 8 + (k & 7)]);
          part += (accy[m][c][r] + 2.f * vv[c]) * xv;
        }
        part += __shfl_xor(part, 1); part += __shfl_xor(part, 2);
        part += __shfl_xor(part, 4); part += __shfl_xor(part, 8);
        if (lr == 0) atomicAdd(&nrm_lds[row], part);
      }
  }

  // ---- Phase W: in-graph window logits (handles graph-straddling tiles) ----
  {
    int g0 = n0 / NPG;
    int g1 = (n0 + 31) / NPG;
    for (int gp = g0; gp <= g1; ++gp) {
      int wb = gp * KPC;
      f32x4 accw[2] = {};
      #pragma unroll
      for (int kt = 0; kt < 8; ++kt) {
        bfrag a[2], bfr;
        #pragma unroll
        for (int m = 0; m < 2; ++m) {
          int slot = (m * 16 + lr) * 32 + kt * 4 + lg;
          a[m] = *reinterpret_cast<const bfrag*>(&xs4[slot ^ ((slot >> 5) & 7)]);
        }
        bfr = *reinterpret_cast<const bfrag*>(Wtp + (size_t)(wb + wid * 16 + lr) * KK2 + kt * 32 + lg * 8);
        #pragma unroll
        for (int m = 0; m < 2; ++m)
          accw[m] = __builtin_amdgcn_mfma_f32_16x16x32_bf16(a[m], bfr, accw[m], 0, 0, 0);
      }
      int wc = wid * 16 + lr;
      float bias = (wc < KPC) ? bp[wb + wc] : 0.f;
      #pragma unroll
      for (int m = 0; m < 2; ++m)
        #pragma unroll
        for (int r = 0; r < 4; ++r) {
          int row = m * 16 + lg * 4 + r;
          if (wc < KPC && (n0 + row) / NPG == gp)
            zbuf[row][wc] = accw[m][r] + bias;
        }
    }
  }

  // ---- Phase F: feat GEMM, cols wid*32..+32 ----
  f32x4 accf[2][2] = {};
  {
    #pragma unroll
    for (int kt = 0; kt < 8; ++kt) {
      bfrag a[2], bfr[2];
      #pragma unroll
      for (int m = 0; m < 2; ++m) {
        int slot = (m * 16 + lr) * 32 + kt * 4 + lg;
        a[m] = *reinterpret_cast<const bfrag*>(&xs4[slot ^ ((slot >> 5) & 7)]);
      }
      #pragma unroll
      for (int c = 0; c < 2; ++c) {
        int col = wid * 32 + c * 16 + lr;
        bfr[c] = *reinterpret_cast<const bfrag*>(Wtf + (size_t)col * KK2 + kt * 32 + lg * 8);
      }
      #pragma unroll
      for (int m = 0; m < 2; ++m)
        #pragma unroll
        for (int c = 0; c < 2; ++c)
          accf[m][c] = __builtin_amdgcn_mfma_f32_16x16x32_bf16(a[m], bfr[c], accf[m][c], 0, 0, 0);
    }
    float nf[2][4] = {};
    #pragma unroll
    for (int c = 0; c < 2; ++c) {
      int col = wid * 32 + c * 16 + lr;
      float bias = bfeat[col];
      #pragma unroll
      for (int m = 0; m < 2; ++m)
        #pragma unroll
        for (int r = 0; r < 4; ++r) {
          float z = accf[m][c][r] + bias;
          accf[m][c][r] = z;
          nf[m][r] += z * z;
        }
    }
    #pragma unroll
    for (int m = 0; m < 2; ++m)
      #pragma unroll
      for (int r = 0; r < 4; ++r) {
        float p = nf[m][r];
        p += __shfl_xor(p, 1); p += __shfl_xor(p, 2);
        p += __shfl_xor(p, 4); p += __shfl_xor(p, 8);
        if (lr == 0) atomicAdd(&nrmf_lds[m * 16 + lg * 4 + r], p);
      }
  }
  __syncthreads();   // nrmf ready; xs4 MFMA reads done -> reuse as ftl

  // feat -> LDS transpose (ftl[col][row], stride 40 ushorts, 16B-aligned rows)
  unsigned short* ftl = (unsigned short*)xs4;
  #pragma unroll
  for (int m = 0; m < 2; ++m)
    #pragma unroll
    for (int r = 0; r < 4; ++r) {
      int row = m * 16 + lg * 4 + r;
      float sc = 1.f / fmaxf(sqrtf(nrmf_lds[row]), 1e-12f);
      #pragma unroll
      for (int c = 0; c < 2; ++c) {
        int col = wid * 32 + c * 16 + lr;
        ftl[col * 40 + row] = f2bf(fmaxf(accf[m][c][r] * sc, 0.f));
      }
    }

  // softmax: 4 threads per node -> p_pad (fp16) and pT (bf16 [g][64][1024])
  if (tid < 128) {
    int node = tid >> 2, q = tid & 3;
    float nv = nrm_lds[node] + bbp[0];
    float inv = 1.f / fmaxf(sqrtf(fmaxf(nv, 0.f)), 1e-12f);
    float e[16];
    float mx = -1e30f;
    #pragma unroll
    for (int i = 0; i < 16; ++i) {
      int cc = q * 16 + i;
      float sv = (cc < KPC) ? fmaxf(zbuf[node][cc] * inv, 0.f) : -1e30f;
      e[i] = sv;
      mx = fmaxf(mx, sv);
    }
    mx = fmaxf(mx, __shfl_xor(mx, 1));
    mx = fmaxf(mx, __shfl_xor(mx, 2));
    float esum = 0.f;
    #pragma unroll
    for (int i = 0; i < 16; ++i) {
      int cc = q * 16 + i;
      float ev = (cc < KPC) ? __expf(e[i] - mx) : 0.f;
      e[i] = ev;
      esum += ev;
    }
    esum += __shfl_xor(esum, 1);
    esum += __shfl_xor(esum, 2);
    float isum = 1.f / esum;
    int n = n0 + node;
    int gg = n / NPG;
    int nloc = n - gg * NPG;
    half8 o0, o1;
    #pragma unroll
    for (int i = 0; i < 8; ++i) {
      o0[i] = (_Float16)(e[i] * isum);
      o1[i] = (_Float16)(e[i + 8] * isum);
    }
    *(half8*)&p_pad[(size_t)n * KPAD + q * 16] = o0;
    *(half8*)&p_pad[(size_t)n * KPAD + q * 16 + 8] = o1;
    #pragma unroll
    for (int i = 0; i < 16; ++i) {
      int cc = q * 16 + i;
      pT[((size_t)gg * KPAD + cc) * NPGP + nloc] = f2bf(e[i] * isum);
    }
  }
  __syncthreads();

  // coalesced featT stores: 2 chunks per thread (128 cols x 4 chunks of 8 nodes)
  #pragma unroll
  for (int pass = 0; pass < 2; ++pass) {
    int ch = tid + pass * 256;
    int col = ch >> 2, off = (ch & 3) * 8;
    *(ushort8*)(featT + (size_t)col * NNT + n0 + off) = *(const ushort8*)&ftl[col * 40 + off];
  }
}

// ================= stage 4: a_s gather -> asT (bf16, transposed) | zero d_out =================
__global__ __launch_bounds__(256) void k_as(
    const _Float16* __restrict__ p_pad, const int* __restrict__ deg,
    const int* __restrict__ ssrc, unsigned short* __restrict__ asT,
    float* __restrict__ out) {
  __shared__ unsigned short as_lds[64 * 40];
  int b = blockIdx.x;
  int tid = threadIdx.x;
  if (b >= 625) {                       // ---- zero d_out (1102 blocks x 1024 floats) ----
    int idx = (b - 625) * 256 + tid;
    if (idx < 282000) ((float4*)out)[idx] = make_float4(0.f, 0.f, 0.f, 0.f);
    return;
  }
  int wg = xcd_swz(b, 625);
  int nrow = tid >> 3;                  // 32 nodes/block
  int n = wg * 32 + nrow;
  int lane = tid & 7;                   // 8 lanes x 8 fp16 = 64 cols
  int dg = deg[n];
  const int* sl = ssrc + n * CAP;
  float a[8] = {};
  int j = 0;
  for (; j + 8 <= dg; j += 8) {         // 8 gathers in flight
    int4 ia = *(const int4*)&sl[j];
    int4 ib = *(const int4*)&sl[j + 4];
    half8 w0 = *(const half8*)(p_pad + (size_t)ia.x * KPAD + lane * 8);
    half8 w1 = *(const half8*)(p_pad + (size_t)ia.y * KPAD + lane * 8);
    half8 w2 = *(const half8*)(p_pad + (size_t)ia.z * KPAD + lane * 8);
    half8 w3 = *(const half8*)(p_pad + (size_t)ia.w * KPAD + lane * 8);
    half8 w4 = *(const half8*)(p_pad + (size_t)ib.x * KPAD + lane * 8);
    half8 w5 = *(const half8*)(p_pad + (size_t)ib.y * KPAD + lane * 8);
    half8 w6 = *(const half8*)(p_pad + (size_t)ib.z * KPAD + lane * 8);
    half8 w7 = *(const half8*)(p_pad + (size_t)ib.w * KPAD + lane * 8);
    #pragma unroll
    for (int i = 0; i < 8; ++i)
      a[i] += (((float)w0[i] + (float)w1[i]) + ((float)w2[i] + (float)w3[i])) +
              (((float)w4[i] + (float)w5[i]) + ((float)w6[i] + (float)w7[i]));
  }
  for (; j + 4 <= dg; j += 4) {
    int4 idx = *(const int4*)&sl[j];
    half8 v0 = *(const half8*)(p_pad + (size_t)idx.x * KPAD + lane * 8);
    half8 v1 = *(const half8*)(p_pad + (size_t)idx.y * KPAD + lane * 8);
    half8 v2 = *(const half8*)(p_pad + (size_t)idx.z * KPAD + lane * 8);
    half8 v3 = *(const half8*)(p_pad + (size_t)idx.w * KPAD + lane * 8);
    #pragma unroll
    for (int i = 0; i < 8; ++i)
      a[i] += (float)v0[i] + (float)v1[i] + (float)v2[i] + (float)v3[i];
  }
  for (; j < dg; ++j) {
    half8 vv = *(const half8*)(p_pad + (size_t)sl[j] * KPAD + lane * 8);
    #pragma unroll
    for (int i = 0; i < 8; ++i) a[i] += (float)vv[i];
  }
  // transpose via LDS, store coalesced: asT[col][node]
  #pragma unroll
  for (int i = 0; i < 8; ++i)
    as_lds[(lane * 8 + i) * 40 + nrow] = f2bf(a[i]);
  __syncthreads();
  {
    int col = tid >> 2, off = (tid & 3) * 8;
    *(ushort8*)(asT + (size_t)col * NNT + wg * 32 + off) = *(const ushort8*)&as_lds[col * 40 + off];
  }
}

// ================= stage 5: split-K per-graph GEMMs, atomic accumulate (160 blocks) =================
__global__ __launch_bounds__(256) void k_final(
    const unsigned short* __restrict__ pT, const unsigned short* __restrict__ featT,
    const unsigned short* __restrict__ asT, float* __restrict__ out) {
  int g = blockIdx.x >> 3;              // 20 graphs x 8 K-chunks
  int kc = blockIdx.x & 7;
  int tid = threadIdx.x;
  int wid = tid >> 6, lane = tid & 63;
  int lr = lane & 15, lg = lane >> 4;
  f32x4 acc[3][4] = {};                 // [col-frag j][row-frag m]
  const unsigned short* bbase[3];
  #pragma unroll
  for (int j = 0; j < 3; ++j) {
    int cf = wid * 3 + j;               // 0..7: h_pool cols cf*16; 8..11: adj cols (cf-8)*16
    bbase[j] = (cf < 8) ? (featT + (size_t)(cf * 16 + lr) * NNT)
                        : (asT + (size_t)((cf - 8) * 16 + lr) * NNT);
  }
  int nb0 = g * NPG + kc * 128;         // global node base of this K-chunk
  #pragma unroll
  for (int ks = 0; ks < 4; ++ks) {
    bfrag a[4], bfr[3];
    #pragma unroll
    for (int m = 0; m < 4; ++m)
      a[m] = *(const bfrag*)(pT + ((size_t)g * KPAD + m * 16 + lr) * NPGP + kc * 128 + ks * 32 + lg * 8);
    #pragma unroll
    for (int j = 0; j < 3; ++j)
      bfr[j] = *(const bfrag*)(bbase[j] + nb0 + ks * 32 + lg * 8);
    #pragma unroll
    for (int j = 0; j < 3; ++j)
      #pragma unroll
      for (int m = 0; m < 4; ++m)
        acc[j][m] = __builtin_amdgcn_mfma_f32_16x16x32_bf16(a[m], bfr[j], acc[j][m], 0, 0, 0);
  }
  #pragma unroll
  for (int j = 0; j < 3; ++j) {
    int cf = wid * 3 + j;
    #pragma unroll
    for (int m = 0; m < 4; ++m)
      #pragma unroll
      for (int r = 0; r < 4; ++r) {
        int i = m * 16 + lg * 4 + r;
        if (i < KPC) {
          if (cf < 8) {
            int col = cf * 16 + lr;
            atomicAdd(&out[1000000 + (size_t)(g * KPC + i) * DD + col], acc[j][m][r]);
          } else {
            int col2 = (cf - 8) * 16 + lr;
            if (col2 < KPC)
              atomicAdd(&out[(size_t)(g * KPC + i) * NAC + g * KPC + col2], acc[j][m][r]);
          }
        }
      }
  }
}

extern "C" void kernel_launch(void* const* d_in, const int* in_sizes, int n_in,
                              void* d_out, int out_size, void* d_ws, size_t ws_size,
                              hipStream_t stream) {
  const float* h = (const float*)d_in[0];
  const float* Wf = (const float*)d_in[1];
  const float* bf = (const float*)d_in[2];
  const float* Wp = (const float*)d_in[3];
  const float* bp = (const float*)d_in[4];
  const int* src = (const int*)d_in[5];
  const int* dst = (const int*)d_in[6];
  // d_in[7] (mask) unused: block-diagonal by construction.
  float* out = (float*)d_out;
  char* ws = (char*)d_ws;

  int* deg = (int*)(ws + 0);                                // 80 KB
  int* ssrc = (int*)(ws + 80000);                           // 7.68 MB
  unsigned short* xb = (unsigned short*)(ws + 7760000);     // 10.24 MB
  _Float16* p_pad = (_Float16*)(ws + 18000000);             // 2.56 MB
  unsigned short* featT = (unsigned short*)(ws + 20560000); // [128][20480] bf16 = 5.24 MB
  unsigned short* asT = (unsigned short*)(ws + 25802880);   // [64][20480] bf16 = 2.62 MB
  unsigned short* Wpb = (unsigned short*)(ws + 28424320);   // 512 KB
  unsigned short* Gb = (unsigned short*)(ws + 28948608);    // 128 KB
  float* v = (float*)(ws + 29079680);                       // 1 KB
  float* bb = (float*)(ws + 29080704);                      // 1 KB
  unsigned short* Wtp = (unsigned short*)(ws + 29081728);   // 512 KB
  unsigned short* Wtf = (unsigned short*)(ws + 29606016);   // 64 KB
  unsigned short* pT = (unsigned short*)(ws + 29671552);    // 2.62 MB

  hipMemsetAsync(deg, 0, 80000, stream);

  k_prep<<<5062, 256, 0, stream>>>(h, Wf, Wp, bp, src, dst, deg, ssrc, xb, Wtp, Wtf, Wpb, v, bb, pT);
  k_mid<<<1266, 256, 0, stream>>>(Wpb, Gb, deg, ssrc, xb);
  k_fused<<<625, 256, 0, stream>>>(xb, Gb, Wtp, Wtf, bp, bf, v, bb, featT, p_pad, pT);
  k_as<<<1727, 256, 0, stream>>>(p_pad, deg, ssrc, asT, out);
  k_final<<<160, 256, 0, stream>>>(pT, featT, asT, out);
}